// Round 7
// baseline (686.650 us; speedup 1.0000x reference)
//
#include <hip/hip_runtime.h>
#include <hip/hip_bf16.h>
#include <math.h>

// Problem constants
#define Bv   4
#define LQv  1024
#define Cv   256
#define Hv   8
#define Lv   4
#define Pv   4
#define DFFv 1024
#define DHv  32
#define LSRCv 21760   // 128*128 + 64*64 + 32*32 + 16*16

typedef __attribute__((ext_vector_type(8))) short bhalf8;   // 8 bf16 (4 VGPRs)
typedef __attribute__((ext_vector_type(4))) float floatx4;  // MFMA acc

// fp32 -> bf16 RNE, packed pair
__device__ inline unsigned pk_bf16x2(float x, float y) {
    unsigned xb = __float_as_uint(x), yb = __float_as_uint(y);
    unsigned xr = (xb + 0x7FFFu + ((xb >> 16) & 1u)) >> 16;
    unsigned yr = (yb + 0x7FFFu + ((yb >> 16) & 1u)) >> 16;
    return xr | (yr << 16);
}
__device__ inline unsigned short bf16_1(float x) {
    unsigned xb = __float_as_uint(x);
    return (unsigned short)((xb + 0x7FFFu + ((xb >> 16) & 1u)) >> 16);
}
__device__ inline float ubf2f(unsigned short u) {
    return __uint_as_float(((unsigned)u) << 16);
}
union frag_cvt { uint4 u; bhalf8 h; };

// ---------------------------------------------------------------------------
// LDS-free bf16-MFMA GEMM: C[M,N] = (A[+A2])[M,K] @ W[N,K]^T + bias[N].
// Each wave owns a 64x64 tile (4x4 frags of 16x16x32); fragments are loaded
// DIRECTLY from global: for frag (row16, k-range), the wave's 64 lanes cover
// 16 rows x 128 contiguous bytes -> fully coalesced dwordx4 loads, L1/L2
// absorb the 2x intra-block re-read. No LDS, no barriers, no bank conflicts;
// waves free-run and self-pipeline across K. fp32->bf16 convert in regs.
// Block 256 thr = 2x2 waves = 128x128 tile. M%128==0, N%128==0, K%32==0.
__global__ __launch_bounds__(256, 2) void gemm_mfma(const float* __restrict__ A,
                                                    const float* __restrict__ A2,
                                                    const float* __restrict__ W,
                                                    const float* __restrict__ bias,
                                                    float* __restrict__ Cf,
                                                    unsigned short* __restrict__ Ch,
                                                    int M, int N, int K, int relu) {
    const int bm = blockIdx.y * 128;
    const int bn = blockIdx.x * 128;
    const int tid = threadIdx.x;
    const int wid = tid >> 6, lane = tid & 63;
    const int wm = (wid >> 1) * 64, wn = (wid & 1) * 64;
    const int col16 = lane & 15;
    const int quad = lane >> 4;

    const float* arow = A + (size_t)(bm + wm + col16) * K + quad * 8;
    const float* a2row = A2 ? A2 + (size_t)(bm + wm + col16) * K + quad * 8 : nullptr;
    const float* wrow = W + (size_t)(bn + wn + col16) * K + quad * 8;
    const size_t rstep = (size_t)16 * K;

    floatx4 acc[4][4] = {};

#pragma unroll 1
    for (int kc = 0; kc < K; kc += 32) {
        bhalf8 af[4], bf[4];
#pragma unroll
        for (int mt = 0; mt < 4; ++mt) {
            const float* p = arow + mt * rstep + kc;
            float4 x0 = *(const float4*)p;
            float4 x1 = *(const float4*)(p + 4);
            if (a2row) {
                const float* p2 = a2row + mt * rstep + kc;
                float4 y0 = *(const float4*)p2;
                float4 y1 = *(const float4*)(p2 + 4);
                x0.x += y0.x; x0.y += y0.y; x0.z += y0.z; x0.w += y0.w;
                x1.x += y1.x; x1.y += y1.y; x1.z += y1.z; x1.w += y1.w;
            }
            frag_cvt c;
            c.u = uint4{pk_bf16x2(x0.x, x0.y), pk_bf16x2(x0.z, x0.w),
                        pk_bf16x2(x1.x, x1.y), pk_bf16x2(x1.z, x1.w)};
            af[mt] = c.h;
        }
#pragma unroll
        for (int nt = 0; nt < 4; ++nt) {
            const float* p = wrow + nt * rstep + kc;
            float4 x0 = *(const float4*)p;
            float4 x1 = *(const float4*)(p + 4);
            frag_cvt c;
            c.u = uint4{pk_bf16x2(x0.x, x0.y), pk_bf16x2(x0.z, x0.w),
                        pk_bf16x2(x1.x, x1.y), pk_bf16x2(x1.z, x1.w)};
            bf[nt] = c.h;
        }
#pragma unroll
        for (int mt = 0; mt < 4; ++mt)
#pragma unroll
            for (int nt = 0; nt < 4; ++nt)
                acc[mt][nt] = __builtin_amdgcn_mfma_f32_16x16x32_bf16(
                    af[mt], bf[nt], acc[mt][nt], 0, 0, 0);
    }

    // epilogue: D row = quad*4 + i, col = col16
#pragma unroll
    for (int mt = 0; mt < 4; ++mt) {
#pragma unroll
        for (int nt = 0; nt < 4; ++nt) {
            const int col = bn + wn + nt * 16 + col16;
            const float bv = bias[col];
#pragma unroll
            for (int i = 0; i < 4; ++i) {
                const int row = bm + wm + mt * 16 + quad * 4 + i;
                float v = acc[mt][nt][i] + bv;
                if (relu) v = fmaxf(v, 0.f);
                if (Ch) Ch[(size_t)row * N + col] = bf16_1(v);
                else    Cf[(size_t)row * N + col] = v;
            }
        }
    }
}

// ---------------------------------------------------------------------------
// MFMA flash self-attention. grid (LQ/64, H, B), block 256 = 4 waves.
// Q/K read with configurable row stride (they live in one [M,512] buffer).
#define ATT_SCALE 0.17677669529663687f
__global__ __launch_bounds__(256, 2) void attn_mfma(const float* __restrict__ Q,
                                                    const float* __restrict__ Kb,
                                                    const float* __restrict__ Vb,
                                                    float* __restrict__ O,
                                                    int qk_stride) {
    const int b = blockIdx.z, h = blockIdx.y, qt = blockIdx.x;
    const int tid = threadIdx.x;
    const int wid = tid >> 6, lane = tid & 63;
    const int col16 = lane & 15, quad = lane >> 4;

    __shared__ unsigned short smem_us[40960];
    unsigned short* Ks = smem_us + wid * 9600;
    unsigned short* Vt = Ks + 2560;
    unsigned short* Ps = Ks + 4864;
    float* corr_s = (float*)(Ks + 9472);
    unsigned short* Qs = smem_us + 38400;

    // ---- stage Q (scaled) once, whole block
    {
        const int row = tid >> 2, part = tid & 3;
        const float* qsrc = Q + ((size_t)(b * LQv + qt * 64 + row)) * qk_stride + h * DHv + part * 8;
        float4 qa = *(const float4*)qsrc;
        float4 qb2 = *(const float4*)(qsrc + 4);
        uint4 qp = {pk_bf16x2(qa.x * ATT_SCALE, qa.y * ATT_SCALE),
                    pk_bf16x2(qa.z * ATT_SCALE, qa.w * ATT_SCALE),
                    pk_bf16x2(qb2.x * ATT_SCALE, qb2.y * ATT_SCALE),
                    pk_bf16x2(qb2.z * ATT_SCALE, qb2.w * ATT_SCALE)};
        *(uint4*)&Qs[row * 40 + part * 8] = qp;
    }
    __syncthreads();
    bhalf8 qfr[4];
#pragma unroll
    for (int j = 0; j < 4; ++j)
        qfr[j] = *(const bhalf8*)&Qs[(j * 16 + col16) * 40 + quad * 8];

    float m_state[4] = {-1e30f, -1e30f, -1e30f, -1e30f};
    float l_state[4] = {0.f, 0.f, 0.f, 0.f};
    floatx4 acc_o[4][2] = {};
    const int dd = lane & 31, half = lane >> 5;

    const float* kbase = Kb + ((size_t)(b * LQv + wid * 256)) * qk_stride + h * DHv;
    const float* vbase = Vb + ((size_t)(b * LQv + wid * 256)) * Cv + h * DHv;

#pragma unroll 1
    for (int t = 0; t < 4; ++t) {
        {
            const float* ks = kbase + (size_t)(t * 64 + lane) * qk_stride;
            float4 f0 = *(const float4*)(ks + 0),  f1 = *(const float4*)(ks + 4);
            float4 f2 = *(const float4*)(ks + 8),  f3 = *(const float4*)(ks + 12);
            float4 f4 = *(const float4*)(ks + 16), f5 = *(const float4*)(ks + 20);
            float4 f6 = *(const float4*)(ks + 24), f7 = *(const float4*)(ks + 28);
            uint4 p0 = {pk_bf16x2(f0.x, f0.y), pk_bf16x2(f0.z, f0.w),
                        pk_bf16x2(f1.x, f1.y), pk_bf16x2(f1.z, f1.w)};
            uint4 p1 = {pk_bf16x2(f2.x, f2.y), pk_bf16x2(f2.z, f2.w),
                        pk_bf16x2(f3.x, f3.y), pk_bf16x2(f3.z, f3.w)};
            uint4 p2 = {pk_bf16x2(f4.x, f4.y), pk_bf16x2(f4.z, f4.w),
                        pk_bf16x2(f5.x, f5.y), pk_bf16x2(f5.z, f5.w)};
            uint4 p3 = {pk_bf16x2(f6.x, f6.y), pk_bf16x2(f6.z, f6.w),
                        pk_bf16x2(f7.x, f7.y), pk_bf16x2(f7.z, f7.w)};
            *(uint4*)&Ks[lane * 40 + 0]  = p0;
            *(uint4*)&Ks[lane * 40 + 8]  = p1;
            *(uint4*)&Ks[lane * 40 + 16] = p2;
            *(uint4*)&Ks[lane * 40 + 24] = p3;
        }
        {
            const float* vs = vbase + (size_t)(t * 64 + half * 32) * Cv + dd;
#pragma unroll
            for (int j4 = 0; j4 < 8; ++j4) {
                float g0 = vs[(j4 * 4 + 0) * Cv], g1 = vs[(j4 * 4 + 1) * Cv];
                float g2 = vs[(j4 * 4 + 2) * Cv], g3 = vs[(j4 * 4 + 3) * Cv];
                uint2 vp = {pk_bf16x2(g0, g1), pk_bf16x2(g2, g3)};
                *(uint2*)&Vt[dd * 72 + half * 32 + j4 * 4] = vp;
            }
        }

        floatx4 accs[4][4] = {};
        bhalf8 af[4];
#pragma unroll
        for (int kf = 0; kf < 4; ++kf)
            af[kf] = *(const bhalf8*)&Ks[(kf * 16 + col16) * 40 + quad * 8];
#pragma unroll
        for (int kf = 0; kf < 4; ++kf)
#pragma unroll
            for (int qf = 0; qf < 4; ++qf)
                accs[kf][qf] = __builtin_amdgcn_mfma_f32_16x16x32_bf16(
                    af[kf], qfr[qf], accs[kf][qf], 0, 0, 0);

#pragma unroll
        for (int qf = 0; qf < 4; ++qf) {
            float tmax = -1e30f;
#pragma unroll
            for (int kf = 0; kf < 4; ++kf) {
                tmax = fmaxf(tmax, fmaxf(fmaxf(accs[kf][qf][0], accs[kf][qf][1]),
                                         fmaxf(accs[kf][qf][2], accs[kf][qf][3])));
            }
            tmax = fmaxf(tmax, __shfl_xor(tmax, 16));
            tmax = fmaxf(tmax, __shfl_xor(tmax, 32));
            float mnew = fmaxf(m_state[qf], tmax);
            float cr = __expf(m_state[qf] - mnew);
            m_state[qf] = mnew;
            float psum = 0.f;
#pragma unroll
            for (int kf = 0; kf < 4; ++kf) {
                float p0 = __expf(accs[kf][qf][0] - mnew);
                float p1 = __expf(accs[kf][qf][1] - mnew);
                float p2 = __expf(accs[kf][qf][2] - mnew);
                float p3 = __expf(accs[kf][qf][3] - mnew);
                psum += (p0 + p1) + (p2 + p3);
                uint2 pp = {pk_bf16x2(p0, p1), pk_bf16x2(p2, p3)};
                *(uint2*)&Ps[(qf * 16 + col16) * 72 + kf * 16 + quad * 4] = pp;
            }
            psum += __shfl_xor(psum, 16);
            psum += __shfl_xor(psum, 32);
            l_state[qf] = l_state[qf] * cr + psum;
            if (quad == 0) corr_s[qf * 16 + col16] = cr;
        }

#pragma unroll
        for (int mf = 0; mf < 4; ++mf) {
            float4 cv = *(const float4*)&corr_s[mf * 16 + quad * 4];
#pragma unroll
            for (int nf = 0; nf < 2; ++nf) {
                acc_o[mf][nf][0] *= cv.x;
                acc_o[mf][nf][1] *= cv.y;
                acc_o[mf][nf][2] *= cv.z;
                acc_o[mf][nf][3] *= cv.w;
            }
        }
#pragma unroll
        for (int ks2 = 0; ks2 < 2; ++ks2) {
            bhalf8 pf[4], vf[2];
#pragma unroll
            for (int mf = 0; mf < 4; ++mf)
                pf[mf] = *(const bhalf8*)&Ps[(mf * 16 + col16) * 72 + ks2 * 32 + quad * 8];
#pragma unroll
            for (int nf = 0; nf < 2; ++nf)
                vf[nf] = *(const bhalf8*)&Vt[(nf * 16 + col16) * 72 + ks2 * 32 + quad * 8];
#pragma unroll
            for (int mf = 0; mf < 4; ++mf)
#pragma unroll
                for (int nf = 0; nf < 2; ++nf)
                    acc_o[mf][nf] = __builtin_amdgcn_mfma_f32_16x16x32_bf16(
                        pf[mf], vf[nf], acc_o[mf][nf], 0, 0, 0);
        }
    }

    __syncthreads();
    float* mbuf = (float*)smem_us;
    float* lbuf = mbuf + 256;
    float* obuf = lbuf + 256;
    if (quad == 0) {
#pragma unroll
        for (int qf = 0; qf < 4; ++qf) {
            mbuf[wid * 64 + qf * 16 + col16] = m_state[qf];
            lbuf[wid * 64 + qf * 16 + col16] = l_state[qf];
        }
    }
#pragma unroll
    for (int mf = 0; mf < 4; ++mf)
#pragma unroll
        for (int nf = 0; nf < 2; ++nf)
#pragma unroll
            for (int i = 0; i < 4; ++i)
                obuf[wid * 2048 + (mf * 16 + quad * 4 + i) * 32 + nf * 16 + col16] =
                    acc_o[mf][nf][i];
    __syncthreads();
    {
        const int q = tid >> 2, dg = (tid & 3) * 8;
        float m0 = mbuf[q], m1 = mbuf[64 + q], m2 = mbuf[128 + q], m3 = mbuf[192 + q];
        float gm = fmaxf(fmaxf(m0, m1), fmaxf(m2, m3));
        float e0 = __expf(m0 - gm), e1 = __expf(m1 - gm);
        float e2 = __expf(m2 - gm), e3 = __expf(m3 - gm);
        float lt = lbuf[q] * e0 + lbuf[64 + q] * e1 + lbuf[128 + q] * e2 + lbuf[192 + q] * e3;
        float inv = 1.f / lt;
        const float* o0 = obuf + q * 32 + dg;
        float* orow = O + ((size_t)(b * LQv + qt * 64 + q)) * Cv + h * DHv + dg;
        float ov[8];
#pragma unroll
        for (int d = 0; d < 8; ++d)
            ov[d] = (o0[d] * e0 + o0[2048 + d] * e1 + o0[4096 + d] * e2 + o0[6144 + d] * e3) * inv;
        *(float4*)(orow) = make_float4(ov[0], ov[1], ov[2], ov[3]);
        *(float4*)(orow + 4) = make_float4(ov[4], ov[5], ov[6], ov[7]);
    }
}

// ---------------------------------------------------------------------------
// Deformable sampling over bf16 value. grid: B*LQ blocks, 256 thr = (h, d).
__global__ __launch_bounds__(256) void deform_sample(const unsigned short* __restrict__ value,
                                                     const float* __restrict__ offs,
                                                     const float* __restrict__ awl,
                                                     const float* __restrict__ ref,
                                                     float* __restrict__ out) {
    const int bq = blockIdx.x;          // b*LQ + q
    const int b = bq >> 10;
    const int tid = threadIdx.x;
    const int h = tid >> 5, d = tid & 31;

    const float* aw = awl + (size_t)bq * (Hv * Lv * Pv) + h * 16;
    float w[16];
    float mx = -1e30f;
#pragma unroll
    for (int j = 0; j < 16; ++j) { w[j] = aw[j]; mx = fmaxf(mx, w[j]); }
    float ssum = 0.f;
#pragma unroll
    for (int j = 0; j < 16; ++j) { w[j] = __expf(w[j] - mx); ssum += w[j]; }
    float invs = 1.f / ssum;

    const float* op = offs + (size_t)bq * 256 + h * 32;
    const float* rp = ref + (size_t)bq * (Lv * 2);

    const int starts[4] = {0, 16384, 20480, 21504};
    const int WHl[4] = {128, 64, 32, 16};

    float acc = 0.f;
#pragma unroll 1
    for (int l = 0; l < 4; ++l) {
        const int wl = WHl[l];
        const float rx = rp[l * 2 + 0], ry = rp[l * 2 + 1];
        const unsigned short* vb0 = value + ((size_t)b * LSRCv + starts[l]) * Cv + h * DHv + d;
#pragma unroll 1
        for (int p = 0; p < 4; ++p) {
            float ox = op[l * 8 + p * 2 + 0], oy = op[l * 8 + p * 2 + 1];
            float x = rx * (float)wl + ox - 0.5f;
            float y = ry * (float)wl + oy - 0.5f;
            float fx0 = floorf(x), fy0 = floorf(y);
            int x0 = (int)fx0, y0 = (int)fy0;
            float tx = x - fx0, ty = y - fy0;
            float w00 = (1.f - tx) * (1.f - ty);
            float w10 = tx * (1.f - ty);
            float w01 = (1.f - tx) * ty;
            float w11 = tx * ty;
            float s = 0.f;
            bool xin0 = (x0 >= 0) & (x0 < wl);
            bool xin1 = (x0 + 1 >= 0) & (x0 + 1 < wl);
            bool yin0 = (y0 >= 0) & (y0 < wl);
            bool yin1 = (y0 + 1 >= 0) & (y0 + 1 < wl);
            if (yin0) {
                if (xin0) s = fmaf(w00, ubf2f(vb0[(size_t)(y0 * wl + x0) * Cv]), s);
                if (xin1) s = fmaf(w10, ubf2f(vb0[(size_t)(y0 * wl + x0 + 1) * Cv]), s);
            }
            if (yin1) {
                if (xin0) s = fmaf(w01, ubf2f(vb0[(size_t)((y0 + 1) * wl + x0) * Cv]), s);
                if (xin1) s = fmaf(w11, ubf2f(vb0[(size_t)((y0 + 1) * wl + x0 + 1) * Cv]), s);
            }
            acc = fmaf(w[l * 4 + p] * invs, s, acc);
        }
    }
    out[(size_t)bq * Cv + h * DHv + d] = acc;
}

// ---------------------------------------------------------------------------
// out = LayerNorm(x + r) * g + b    one block per row of 256
__global__ __launch_bounds__(256) void ln_residual(const float* __restrict__ x,
                                                   const float* __restrict__ r,
                                                   const float* __restrict__ g,
                                                   const float* __restrict__ bta,
                                                   float* __restrict__ out) {
    const int row = blockIdx.x;
    const int tid = threadIdx.x;
    float v = x[(size_t)row * Cv + tid] + r[(size_t)row * Cv + tid];
    float s = v, sq = v * v;
#pragma unroll
    for (int off = 32; off > 0; off >>= 1) {
        s  += __shfl_down(s, off, 64);
        sq += __shfl_down(sq, off, 64);
    }
    __shared__ float ss[4], sqq[4];
    int wid = tid >> 6;
    if ((tid & 63) == 0) { ss[wid] = s; sqq[wid] = sq; }
    __syncthreads();
    __shared__ float meansh, rstdsh;
    if (tid == 0) {
        float S = ss[0] + ss[1] + ss[2] + ss[3];
        float Q = sqq[0] + sqq[1] + sqq[2] + sqq[3];
        float mean = S * (1.f / Cv);
        float var = Q * (1.f / Cv) - mean * mean;
        meansh = mean;
        rstdsh = rsqrtf(var + 1e-5f);
    }
    __syncthreads();
    out[(size_t)row * Cv + tid] = (v - meansh) * rstdsh * g[tid] + bta[tid];
}

// ---------------------------------------------------------------------------
extern "C" void kernel_launch(void* const* d_in, const int* in_sizes, int n_in,
                              void* d_out, int out_size, void* d_ws, size_t ws_size,
                              hipStream_t stream) {
    const float* tgt       = (const float*)d_in[0];
    const float* query_pos = (const float*)d_in[1];
    const float* ref_pts   = (const float*)d_in[2];
    const float* src       = (const float*)d_in[3];
    const float* in_w      = (const float*)d_in[4];
    const float* in_b      = (const float*)d_in[5];
    const float* sa_w      = (const float*)d_in[6];
    const float* sa_b      = (const float*)d_in[7];
    const float* off_w     = (const float*)d_in[8];
    const float* off_b     = (const float*)d_in[9];
    const float* aw_w      = (const float*)d_in[10];
    const float* aw_b      = (const float*)d_in[11];
    const float* val_w     = (const float*)d_in[12];
    const float* val_b     = (const float*)d_in[13];
    const float* co_w      = (const float*)d_in[14];
    const float* co_b      = (const float*)d_in[15];
    const float* ln1_g     = (const float*)d_in[16];
    const float* ln1_b     = (const float*)d_in[17];
    const float* ln2_g     = (const float*)d_in[18];
    const float* ln2_b     = (const float*)d_in[19];
    const float* ln3_g     = (const float*)d_in[20];
    const float* ln3_b     = (const float*)d_in[21];
    const float* f1_w      = (const float*)d_in[22];
    const float* f1_b      = (const float*)d_in[23];
    const float* f2_w      = (const float*)d_in[24];
    const float* f2_b      = (const float*)d_in[25];

    const int M0  = Bv * LQv * Cv;          // 1048576
    const int VSZ = Bv * LSRCv * Cv;        // 22282240
    float* ws = (float*)d_ws;

    // Phase-A buffers alias the (later) bf16 value region — lifetimes disjoint.
    float* big    = ws;                     // VSZ floats
    float* qkbuf  = big;                    // [4096][512]: q cols 0-255, k 256-511
    float* vb     = big + (size_t)2 * M0;
    float* ob     = big + (size_t)3 * M0;
    unsigned short* value16 = (unsigned short*)big;   // VSZ ushorts (phase B)
    float* tgt_a  = ws + (size_t)VSZ;
    float* offs   = tgt_a + M0;
    float* awb    = offs + M0;              // B*LQ*128
    float* sampled= awb + (size_t)Bv * LQv * 128;
    float* tgt_b  = sampled + M0;
    float* hidden = tgt_b + M0;             // B*LQ*DFF
    float* tmp    = hidden + (size_t)Bv * LQv * DFFv;

    const int Mq = Bv * LQv;                // 4096 rows
    dim3 blk256(256);

    // 1. fused q+k projection: A = tgt + query_pos, W = in_w rows 0-511
    gemm_mfma<<<dim3(512 / 128, Mq / 128), blk256, 0, stream>>>(
        tgt, query_pos, in_w, in_b, qkbuf, nullptr, Mq, 512, Cv, 0);
    // 2. v projection
    gemm_mfma<<<dim3(Cv / 128, Mq / 128), blk256, 0, stream>>>(
        tgt, nullptr, in_w + (size_t)2 * Cv * Cv, in_b + 2 * Cv, vb, nullptr, Mq, Cv, Cv, 0);

    // 3. self-attention (MFMA flash; Q/K strided in qkbuf)
    attn_mfma<<<dim3(LQv / 64, Hv, Bv), blk256, 0, stream>>>(qkbuf, qkbuf + 256, vb, ob, 512);

    // 4. output projection, 5. LN2 residual
    gemm_mfma<<<dim3(Cv / 128, Mq / 128), blk256, 0, stream>>>(
        ob, nullptr, sa_w, sa_b, tmp, nullptr, Mq, Cv, Cv, 0);
    ln_residual<<<dim3(Mq), blk256, 0, stream>>>(tgt, tmp, ln2_g, ln2_b, tgt_a);

    // 6. value projection (big GEMM) -> bf16
    gemm_mfma<<<dim3(Cv / 128, (Bv * LSRCv) / 128), blk256, 0, stream>>>(
        src, nullptr, val_w, val_b, nullptr, value16, Bv * LSRCv, Cv, Cv, 0);

    // 7. offsets + aw logits (fused add A = tgt_a + query_pos)
    gemm_mfma<<<dim3(Cv / 128, Mq / 128), blk256, 0, stream>>>(
        tgt_a, query_pos, off_w, off_b, offs, nullptr, Mq, Cv, Cv, 0);
    gemm_mfma<<<dim3(128 / 128, Mq / 128), blk256, 0, stream>>>(
        tgt_a, query_pos, aw_w, aw_b, awb, nullptr, Mq, 128, Cv, 0);

    // 8. deformable bilinear sampling (bf16 value)
    deform_sample<<<dim3(Bv * LQv), blk256, 0, stream>>>(value16, offs, awb, ref_pts, sampled);

    // 9. cross-attn output projection, LN1 residual
    gemm_mfma<<<dim3(Cv / 128, Mq / 128), blk256, 0, stream>>>(
        sampled, nullptr, co_w, co_b, tmp, nullptr, Mq, Cv, Cv, 0);
    ln_residual<<<dim3(Mq), blk256, 0, stream>>>(tgt_a, tmp, ln1_g, ln1_b, tgt_b);

    // 10. FFN + LN3 -> d_out
    gemm_mfma<<<dim3(DFFv / 128, Mq / 128), blk256, 0, stream>>>(
        tgt_b, nullptr, f1_w, f1_b, hidden, nullptr, Mq, DFFv, Cv, 1);
    gemm_mfma<<<dim3(Cv / 128, Mq / 128), blk256, 0, stream>>>(
        hidden, nullptr, f2_w, f2_b, tmp, nullptr, Mq, Cv, DFFv, 0);
    ln_residual<<<dim3(Mq), blk256, 0, stream>>>(tgt_b, tmp, ln3_g, ln3_b, (float*)d_out);
}

// Round 8
// 541.104 us; speedup vs baseline: 1.2690x; 1.2690x over previous
//
#include <hip/hip_runtime.h>
#include <hip/hip_bf16.h>
#include <math.h>

// Problem constants
#define Bv   4
#define LQv  1024
#define Cv   256
#define Hv   8
#define Lv   4
#define Pv   4
#define DFFv 1024
#define DHv  32
#define LSRCv 21760   // 128*128 + 64*64 + 32*32 + 16*16

typedef __attribute__((ext_vector_type(8))) short bhalf8;   // 8 bf16 (4 VGPRs)
typedef __attribute__((ext_vector_type(4))) float floatx4;  // MFMA acc

// fp32 -> bf16 RNE, packed pair
__device__ inline unsigned pk_bf16x2(float x, float y) {
    unsigned xb = __float_as_uint(x), yb = __float_as_uint(y);
    unsigned xr = (xb + 0x7FFFu + ((xb >> 16) & 1u)) >> 16;
    unsigned yr = (yb + 0x7FFFu + ((yb >> 16) & 1u)) >> 16;
    return xr | (yr << 16);
}
__device__ inline unsigned short bf16_1(float x) {
    unsigned xb = __float_as_uint(x);
    return (unsigned short)((xb + 0x7FFFu + ((xb >> 16) & 1u)) >> 16);
}
__device__ inline float ubf2f(unsigned short u) {
    return __uint_as_float(((unsigned)u) << 16);
}

// ---------------------------------------------------------------------------
// Single-wave bf16-MFMA GEMM: C = (A[+A2]) @ W^T + bias, optional relu,
// optional bf16 output. Block = 64 threads = ONE wave owning a 64x64 tile.
// - LDS staging is wave-private: ds_write -> ds_read needs NO barrier
//   (same-wave DS ordering; same pattern as attn's P round-trip).
// - Register prefetch of next K-tile overlaps global latency with MFMA.
// - Grid (N/64, M/64): >=256 blocks for all our shapes -> all CUs busy.
// M%64==0, N%64==0, K%32==0.
__global__ __launch_bounds__(64) void gemm_wave(const float* __restrict__ A,
                                                const float* __restrict__ A2,
                                                const float* __restrict__ W,
                                                const float* __restrict__ bias,
                                                float* __restrict__ Cf,
                                                unsigned short* __restrict__ Ch,
                                                int M, int N, int K, int relu) {
    __shared__ unsigned short As[64 * 40];   // 64 rows x 32 bf16 (+8 pad)
    __shared__ unsigned short Bs[64 * 40];
    const int bm = blockIdx.y * 64;
    const int bn = blockIdx.x * 64;
    const int lane = threadIdx.x;
    const int col16 = lane & 15, quad = lane >> 4;

    // staging: lane = row; 32 floats (one BK-slab of its row) per operand
    const float* aptr = A + (size_t)(bm + lane) * K;
    const float* a2ptr = A2 ? A2 + (size_t)(bm + lane) * K : nullptr;
    const float* wptr = W + (size_t)(bn + lane) * K;

    float4 av[8], wv[8];
    auto ld = [&](int kc) {
        const float4* ap = (const float4*)(aptr + kc);
        const float4* wp = (const float4*)(wptr + kc);
#pragma unroll
        for (int i = 0; i < 8; ++i) { av[i] = ap[i]; wv[i] = wp[i]; }
        if (a2ptr) {
            const float4* p2 = (const float4*)(a2ptr + kc);
#pragma unroll
            for (int i = 0; i < 8; ++i) {
                float4 t = p2[i];
                av[i].x += t.x; av[i].y += t.y; av[i].z += t.z; av[i].w += t.w;
            }
        }
    };

    floatx4 acc[4][4] = {};
    ld(0);
    unsigned* as_dst = (unsigned*)&As[lane * 40];
    unsigned* bs_dst = (unsigned*)&Bs[lane * 40];

#pragma unroll 1
    for (int kc = 0; kc < K; kc += 32) {
        // pack current regs -> LDS (4x b128 per operand)
#pragma unroll
        for (int g = 0; g < 4; ++g) {
            uint4 pa = {pk_bf16x2(av[2*g].x,   av[2*g].y),
                        pk_bf16x2(av[2*g].z,   av[2*g].w),
                        pk_bf16x2(av[2*g+1].x, av[2*g+1].y),
                        pk_bf16x2(av[2*g+1].z, av[2*g+1].w)};
            *(uint4*)(as_dst + 4 * g) = pa;
            uint4 pw = {pk_bf16x2(wv[2*g].x,   wv[2*g].y),
                        pk_bf16x2(wv[2*g].z,   wv[2*g].w),
                        pk_bf16x2(wv[2*g+1].x, wv[2*g+1].y),
                        pk_bf16x2(wv[2*g+1].z, wv[2*g+1].w)};
            *(uint4*)(bs_dst + 4 * g) = pw;
        }
        if (kc + 32 < K) ld(kc + 32);   // prefetch next slab (overlaps MFMA)

        bhalf8 af[4], bf[4];
#pragma unroll
        for (int mt = 0; mt < 4; ++mt)
            af[mt] = *(const bhalf8*)&As[(mt * 16 + col16) * 40 + quad * 8];
#pragma unroll
        for (int nt = 0; nt < 4; ++nt)
            bf[nt] = *(const bhalf8*)&Bs[(nt * 16 + col16) * 40 + quad * 8];
#pragma unroll
        for (int mt = 0; mt < 4; ++mt)
#pragma unroll
            for (int nt = 0; nt < 4; ++nt)
                acc[mt][nt] = __builtin_amdgcn_mfma_f32_16x16x32_bf16(
                    af[mt], bf[nt], acc[mt][nt], 0, 0, 0);
    }

    // epilogue: D row = quad*4 + i, col = col16
#pragma unroll
    for (int mt = 0; mt < 4; ++mt) {
#pragma unroll
        for (int nt = 0; nt < 4; ++nt) {
            const int col = bn + nt * 16 + col16;
            const float bv = bias[col];
#pragma unroll
            for (int i = 0; i < 4; ++i) {
                const int row = bm + mt * 16 + quad * 4 + i;
                float v = acc[mt][nt][i] + bv;
                if (relu) v = fmaxf(v, 0.f);
                if (Ch) Ch[(size_t)row * N + col] = bf16_1(v);
                else    Cf[(size_t)row * N + col] = v;
            }
        }
    }
}

// ---------------------------------------------------------------------------
// MFMA flash self-attention. grid (LQ/64, H, B), block 256 = 4 waves.
// Q/K read with configurable row stride (they live in one [M,512] buffer).
#define ATT_SCALE 0.17677669529663687f
__global__ __launch_bounds__(256, 2) void attn_mfma(const float* __restrict__ Q,
                                                    const float* __restrict__ Kb,
                                                    const float* __restrict__ Vb,
                                                    float* __restrict__ O,
                                                    int qk_stride) {
    const int b = blockIdx.z, h = blockIdx.y, qt = blockIdx.x;
    const int tid = threadIdx.x;
    const int wid = tid >> 6, lane = tid & 63;
    const int col16 = lane & 15, quad = lane >> 4;

    __shared__ unsigned short smem_us[40960];
    unsigned short* Ks = smem_us + wid * 9600;
    unsigned short* Vt = Ks + 2560;
    unsigned short* Ps = Ks + 4864;
    float* corr_s = (float*)(Ks + 9472);
    unsigned short* Qs = smem_us + 38400;

    // ---- stage Q (scaled) once, whole block
    {
        const int row = tid >> 2, part = tid & 3;
        const float* qsrc = Q + ((size_t)(b * LQv + qt * 64 + row)) * qk_stride + h * DHv + part * 8;
        float4 qa = *(const float4*)qsrc;
        float4 qb2 = *(const float4*)(qsrc + 4);
        uint4 qp = {pk_bf16x2(qa.x * ATT_SCALE, qa.y * ATT_SCALE),
                    pk_bf16x2(qa.z * ATT_SCALE, qa.w * ATT_SCALE),
                    pk_bf16x2(qb2.x * ATT_SCALE, qb2.y * ATT_SCALE),
                    pk_bf16x2(qb2.z * ATT_SCALE, qb2.w * ATT_SCALE)};
        *(uint4*)&Qs[row * 40 + part * 8] = qp;
    }
    __syncthreads();
    bhalf8 qfr[4];
#pragma unroll
    for (int j = 0; j < 4; ++j)
        qfr[j] = *(const bhalf8*)&Qs[(j * 16 + col16) * 40 + quad * 8];

    float m_state[4] = {-1e30f, -1e30f, -1e30f, -1e30f};
    float l_state[4] = {0.f, 0.f, 0.f, 0.f};
    floatx4 acc_o[4][2] = {};
    const int dd = lane & 31, half = lane >> 5;

    const float* kbase = Kb + ((size_t)(b * LQv + wid * 256)) * qk_stride + h * DHv;
    const float* vbase = Vb + ((size_t)(b * LQv + wid * 256)) * Cv + h * DHv;

#pragma unroll 1
    for (int t = 0; t < 4; ++t) {
        {
            const float* ks = kbase + (size_t)(t * 64 + lane) * qk_stride;
            float4 f0 = *(const float4*)(ks + 0),  f1 = *(const float4*)(ks + 4);
            float4 f2 = *(const float4*)(ks + 8),  f3 = *(const float4*)(ks + 12);
            float4 f4 = *(const float4*)(ks + 16), f5 = *(const float4*)(ks + 20);
            float4 f6 = *(const float4*)(ks + 24), f7 = *(const float4*)(ks + 28);
            uint4 p0 = {pk_bf16x2(f0.x, f0.y), pk_bf16x2(f0.z, f0.w),
                        pk_bf16x2(f1.x, f1.y), pk_bf16x2(f1.z, f1.w)};
            uint4 p1 = {pk_bf16x2(f2.x, f2.y), pk_bf16x2(f2.z, f2.w),
                        pk_bf16x2(f3.x, f3.y), pk_bf16x2(f3.z, f3.w)};
            uint4 p2 = {pk_bf16x2(f4.x, f4.y), pk_bf16x2(f4.z, f4.w),
                        pk_bf16x2(f5.x, f5.y), pk_bf16x2(f5.z, f5.w)};
            uint4 p3 = {pk_bf16x2(f6.x, f6.y), pk_bf16x2(f6.z, f6.w),
                        pk_bf16x2(f7.x, f7.y), pk_bf16x2(f7.z, f7.w)};
            *(uint4*)&Ks[lane * 40 + 0]  = p0;
            *(uint4*)&Ks[lane * 40 + 8]  = p1;
            *(uint4*)&Ks[lane * 40 + 16] = p2;
            *(uint4*)&Ks[lane * 40 + 24] = p3;
        }
        {
            const float* vs = vbase + (size_t)(t * 64 + half * 32) * Cv + dd;
#pragma unroll
            for (int j4 = 0; j4 < 8; ++j4) {
                float g0 = vs[(j4 * 4 + 0) * Cv], g1 = vs[(j4 * 4 + 1) * Cv];
                float g2 = vs[(j4 * 4 + 2) * Cv], g3 = vs[(j4 * 4 + 3) * Cv];
                uint2 vp = {pk_bf16x2(g0, g1), pk_bf16x2(g2, g3)};
                *(uint2*)&Vt[dd * 72 + half * 32 + j4 * 4] = vp;
            }
        }

        floatx4 accs[4][4] = {};
        bhalf8 af[4];
#pragma unroll
        for (int kf = 0; kf < 4; ++kf)
            af[kf] = *(const bhalf8*)&Ks[(kf * 16 + col16) * 40 + quad * 8];
#pragma unroll
        for (int kf = 0; kf < 4; ++kf)
#pragma unroll
            for (int qf = 0; qf < 4; ++qf)
                accs[kf][qf] = __builtin_amdgcn_mfma_f32_16x16x32_bf16(
                    af[kf], qfr[qf], accs[kf][qf], 0, 0, 0);

#pragma unroll
        for (int qf = 0; qf < 4; ++qf) {
            float tmax = -1e30f;
#pragma unroll
            for (int kf = 0; kf < 4; ++kf) {
                tmax = fmaxf(tmax, fmaxf(fmaxf(accs[kf][qf][0], accs[kf][qf][1]),
                                         fmaxf(accs[kf][qf][2], accs[kf][qf][3])));
            }
            tmax = fmaxf(tmax, __shfl_xor(tmax, 16));
            tmax = fmaxf(tmax, __shfl_xor(tmax, 32));
            float mnew = fmaxf(m_state[qf], tmax);
            float cr = __expf(m_state[qf] - mnew);
            m_state[qf] = mnew;
            float psum = 0.f;
#pragma unroll
            for (int kf = 0; kf < 4; ++kf) {
                float p0 = __expf(accs[kf][qf][0] - mnew);
                float p1 = __expf(accs[kf][qf][1] - mnew);
                float p2 = __expf(accs[kf][qf][2] - mnew);
                float p3 = __expf(accs[kf][qf][3] - mnew);
                psum += (p0 + p1) + (p2 + p3);
                uint2 pp = {pk_bf16x2(p0, p1), pk_bf16x2(p2, p3)};
                *(uint2*)&Ps[(qf * 16 + col16) * 72 + kf * 16 + quad * 4] = pp;
            }
            psum += __shfl_xor(psum, 16);
            psum += __shfl_xor(psum, 32);
            l_state[qf] = l_state[qf] * cr + psum;
            if (quad == 0) corr_s[qf * 16 + col16] = cr;
        }

#pragma unroll
        for (int mf = 0; mf < 4; ++mf) {
            float4 cv = *(const float4*)&corr_s[mf * 16 + quad * 4];
#pragma unroll
            for (int nf = 0; nf < 2; ++nf) {
                acc_o[mf][nf][0] *= cv.x;
                acc_o[mf][nf][1] *= cv.y;
                acc_o[mf][nf][2] *= cv.z;
                acc_o[mf][nf][3] *= cv.w;
            }
        }
#pragma unroll
        for (int ks2 = 0; ks2 < 2; ++ks2) {
            bhalf8 pf[4], vf[2];
#pragma unroll
            for (int mf = 0; mf < 4; ++mf)
                pf[mf] = *(const bhalf8*)&Ps[(mf * 16 + col16) * 72 + ks2 * 32 + quad * 8];
#pragma unroll
            for (int nf = 0; nf < 2; ++nf)
                vf[nf] = *(const bhalf8*)&Vt[(nf * 16 + col16) * 72 + ks2 * 32 + quad * 8];
#pragma unroll
            for (int mf = 0; mf < 4; ++mf)
#pragma unroll
                for (int nf = 0; nf < 2; ++nf)
                    acc_o[mf][nf] = __builtin_amdgcn_mfma_f32_16x16x32_bf16(
                        pf[mf], vf[nf], acc_o[mf][nf], 0, 0, 0);
        }
    }

    __syncthreads();
    float* mbuf = (float*)smem_us;
    float* lbuf = mbuf + 256;
    float* obuf = lbuf + 256;
    if (quad == 0) {
#pragma unroll
        for (int qf = 0; qf < 4; ++qf) {
            mbuf[wid * 64 + qf * 16 + col16] = m_state[qf];
            lbuf[wid * 64 + qf * 16 + col16] = l_state[qf];
        }
    }
#pragma unroll
    for (int mf = 0; mf < 4; ++mf)
#pragma unroll
        for (int nf = 0; nf < 2; ++nf)
#pragma unroll
            for (int i = 0; i < 4; ++i)
                obuf[wid * 2048 + (mf * 16 + quad * 4 + i) * 32 + nf * 16 + col16] =
                    acc_o[mf][nf][i];
    __syncthreads();
    {
        const int q = tid >> 2, dg = (tid & 3) * 8;
        float m0 = mbuf[q], m1 = mbuf[64 + q], m2 = mbuf[128 + q], m3 = mbuf[192 + q];
        float gm = fmaxf(fmaxf(m0, m1), fmaxf(m2, m3));
        float e0 = __expf(m0 - gm), e1 = __expf(m1 - gm);
        float e2 = __expf(m2 - gm), e3 = __expf(m3 - gm);
        float lt = lbuf[q] * e0 + lbuf[64 + q] * e1 + lbuf[128 + q] * e2 + lbuf[192 + q] * e3;
        float inv = 1.f / lt;
        const float* o0 = obuf + q * 32 + dg;
        float* orow = O + ((size_t)(b * LQv + qt * 64 + q)) * Cv + h * DHv + dg;
        float ov[8];
#pragma unroll
        for (int d = 0; d < 8; ++d)
            ov[d] = (o0[d] * e0 + o0[2048 + d] * e1 + o0[4096 + d] * e2 + o0[6144 + d] * e3) * inv;
        *(float4*)(orow) = make_float4(ov[0], ov[1], ov[2], ov[3]);
        *(float4*)(orow + 4) = make_float4(ov[4], ov[5], ov[6], ov[7]);
    }
}

// ---------------------------------------------------------------------------
// Deformable sampling over bf16 value. grid: B*LQ blocks, 256 thr = (h, d).
__global__ __launch_bounds__(256) void deform_sample(const unsigned short* __restrict__ value,
                                                     const float* __restrict__ offs,
                                                     const float* __restrict__ awl,
                                                     const float* __restrict__ ref,
                                                     float* __restrict__ out) {
    const int bq = blockIdx.x;          // b*LQ + q
    const int b = bq >> 10;
    const int tid = threadIdx.x;
    const int h = tid >> 5, d = tid & 31;

    const float* aw = awl + (size_t)bq * (Hv * Lv * Pv) + h * 16;
    float w[16];
    float mx = -1e30f;
#pragma unroll
    for (int j = 0; j < 16; ++j) { w[j] = aw[j]; mx = fmaxf(mx, w[j]); }
    float ssum = 0.f;
#pragma unroll
    for (int j = 0; j < 16; ++j) { w[j] = __expf(w[j] - mx); ssum += w[j]; }
    float invs = 1.f / ssum;

    const float* op = offs + (size_t)bq * 256 + h * 32;
    const float* rp = ref + (size_t)bq * (Lv * 2);

    const int starts[4] = {0, 16384, 20480, 21504};
    const int WHl[4] = {128, 64, 32, 16};

    float acc = 0.f;
#pragma unroll 1
    for (int l = 0; l < 4; ++l) {
        const int wl = WHl[l];
        const float rx = rp[l * 2 + 0], ry = rp[l * 2 + 1];
        const unsigned short* vb0 = value + ((size_t)b * LSRCv + starts[l]) * Cv + h * DHv + d;
#pragma unroll 1
        for (int p = 0; p < 4; ++p) {
            float ox = op[l * 8 + p * 2 + 0], oy = op[l * 8 + p * 2 + 1];
            float x = rx * (float)wl + ox - 0.5f;
            float y = ry * (float)wl + oy - 0.5f;
            float fx0 = floorf(x), fy0 = floorf(y);
            int x0 = (int)fx0, y0 = (int)fy0;
            float tx = x - fx0, ty = y - fy0;
            float w00 = (1.f - tx) * (1.f - ty);
            float w10 = tx * (1.f - ty);
            float w01 = (1.f - tx) * ty;
            float w11 = tx * ty;
            float s = 0.f;
            bool xin0 = (x0 >= 0) & (x0 < wl);
            bool xin1 = (x0 + 1 >= 0) & (x0 + 1 < wl);
            bool yin0 = (y0 >= 0) & (y0 < wl);
            bool yin1 = (y0 + 1 >= 0) & (y0 + 1 < wl);
            if (yin0) {
                if (xin0) s = fmaf(w00, ubf2f(vb0[(size_t)(y0 * wl + x0) * Cv]), s);
                if (xin1) s = fmaf(w10, ubf2f(vb0[(size_t)(y0 * wl + x0 + 1) * Cv]), s);
            }
            if (yin1) {
                if (xin0) s = fmaf(w01, ubf2f(vb0[(size_t)((y0 + 1) * wl + x0) * Cv]), s);
                if (xin1) s = fmaf(w11, ubf2f(vb0[(size_t)((y0 + 1) * wl + x0 + 1) * Cv]), s);
            }
            acc = fmaf(w[l * 4 + p] * invs, s, acc);
        }
    }
    out[(size_t)bq * Cv + h * DHv + d] = acc;
}

// ---------------------------------------------------------------------------
// out = LayerNorm(x + r) * g + b    one block per row of 256
__global__ __launch_bounds__(256) void ln_residual(const float* __restrict__ x,
                                                   const float* __restrict__ r,
                                                   const float* __restrict__ g,
                                                   const float* __restrict__ bta,
                                                   float* __restrict__ out) {
    const int row = blockIdx.x;
    const int tid = threadIdx.x;
    float v = x[(size_t)row * Cv + tid] + r[(size_t)row * Cv + tid];
    float s = v, sq = v * v;
#pragma unroll
    for (int off = 32; off > 0; off >>= 1) {
        s  += __shfl_down(s, off, 64);
        sq += __shfl_down(sq, off, 64);
    }
    __shared__ float ss[4], sqq[4];
    int wid = tid >> 6;
    if ((tid & 63) == 0) { ss[wid] = s; sqq[wid] = sq; }
    __syncthreads();
    __shared__ float meansh, rstdsh;
    if (tid == 0) {
        float S = ss[0] + ss[1] + ss[2] + ss[3];
        float Q = sqq[0] + sqq[1] + sqq[2] + sqq[3];
        float mean = S * (1.f / Cv);
        float var = Q * (1.f / Cv) - mean * mean;
        meansh = mean;
        rstdsh = rsqrtf(var + 1e-5f);
    }
    __syncthreads();
    out[(size_t)row * Cv + tid] = (v - meansh) * rstdsh * g[tid] + bta[tid];
}

// ---------------------------------------------------------------------------
extern "C" void kernel_launch(void* const* d_in, const int* in_sizes, int n_in,
                              void* d_out, int out_size, void* d_ws, size_t ws_size,
                              hipStream_t stream) {
    const float* tgt       = (const float*)d_in[0];
    const float* query_pos = (const float*)d_in[1];
    const float* ref_pts   = (const float*)d_in[2];
    const float* src       = (const float*)d_in[3];
    const float* in_w      = (const float*)d_in[4];
    const float* in_b      = (const float*)d_in[5];
    const float* sa_w      = (const float*)d_in[6];
    const float* sa_b      = (const float*)d_in[7];
    const float* off_w     = (const float*)d_in[8];
    const float* off_b     = (const float*)d_in[9];
    const float* aw_w      = (const float*)d_in[10];
    const float* aw_b      = (const float*)d_in[11];
    const float* val_w     = (const float*)d_in[12];
    const float* val_b     = (const float*)d_in[13];
    const float* co_w      = (const float*)d_in[14];
    const float* co_b      = (const float*)d_in[15];
    const float* ln1_g     = (const float*)d_in[16];
    const float* ln1_b     = (const float*)d_in[17];
    const float* ln2_g     = (const float*)d_in[18];
    const float* ln2_b     = (const float*)d_in[19];
    const float* ln3_g     = (const float*)d_in[20];
    const float* ln3_b     = (const float*)d_in[21];
    const float* f1_w      = (const float*)d_in[22];
    const float* f1_b      = (const float*)d_in[23];
    const float* f2_w      = (const float*)d_in[24];
    const float* f2_b      = (const float*)d_in[25];

    const int M0  = Bv * LQv * Cv;          // 1048576
    const int VSZ = Bv * LSRCv * Cv;        // 22282240
    float* ws = (float*)d_ws;

    // Phase-A buffers alias the (later) bf16 value region — lifetimes disjoint.
    float* big    = ws;                     // VSZ floats
    float* qkbuf  = big;                    // [4096][512]: q cols 0-255, k 256-511
    float* vb     = big + (size_t)2 * M0;
    float* ob     = big + (size_t)3 * M0;
    unsigned short* value16 = (unsigned short*)big;   // VSZ ushorts (phase B)
    float* tgt_a  = ws + (size_t)VSZ;
    float* offs   = tgt_a + M0;
    float* awb    = offs + M0;              // B*LQ*128
    float* sampled= awb + (size_t)Bv * LQv * 128;
    float* tgt_b  = sampled + M0;
    float* hidden = tgt_b + M0;             // B*LQ*DFF
    float* tmp    = hidden + (size_t)Bv * LQv * DFFv;

    const int Mq = Bv * LQv;                // 4096 rows
    dim3 blk256(256);
    dim3 blk64(64);

    // 1. fused q+k projection: A = tgt + query_pos, W = in_w rows 0-511
    gemm_wave<<<dim3(512 / 64, Mq / 64), blk64, 0, stream>>>(
        tgt, query_pos, in_w, in_b, qkbuf, nullptr, Mq, 512, Cv, 0);
    // 2. v projection
    gemm_wave<<<dim3(Cv / 64, Mq / 64), blk64, 0, stream>>>(
        tgt, nullptr, in_w + (size_t)2 * Cv * Cv, in_b + 2 * Cv, vb, nullptr, Mq, Cv, Cv, 0);

    // 3. self-attention (MFMA flash; Q/K strided in qkbuf)
    attn_mfma<<<dim3(LQv / 64, Hv, Bv), blk256, 0, stream>>>(qkbuf, qkbuf + 256, vb, ob, 512);

    // 4. output projection, 5. LN2 residual
    gemm_wave<<<dim3(Cv / 64, Mq / 64), blk64, 0, stream>>>(
        ob, nullptr, sa_w, sa_b, tmp, nullptr, Mq, Cv, Cv, 0);
    ln_residual<<<dim3(Mq), blk256, 0, stream>>>(tgt, tmp, ln2_g, ln2_b, tgt_a);

    // 6. value projection (big GEMM) -> bf16
    gemm_wave<<<dim3(Cv / 64, (Bv * LSRCv) / 64), blk64, 0, stream>>>(
        src, nullptr, val_w, val_b, nullptr, value16, Bv * LSRCv, Cv, Cv, 0);

    // 7. offsets + aw logits (fused add A = tgt_a + query_pos)
    gemm_wave<<<dim3(Cv / 64, Mq / 64), blk64, 0, stream>>>(
        tgt_a, query_pos, off_w, off_b, offs, nullptr, Mq, Cv, Cv, 0);
    gemm_wave<<<dim3(128 / 64, Mq / 64), blk64, 0, stream>>>(
        tgt_a, query_pos, aw_w, aw_b, awb, nullptr, Mq, 128, Cv, 0);

    // 8. deformable bilinear sampling (bf16 value)
    deform_sample<<<dim3(Bv * LQv), blk256, 0, stream>>>(value16, offs, awb, ref_pts, sampled);

    // 9. cross-attn output projection, LN1 residual
    gemm_wave<<<dim3(Cv / 64, Mq / 64), blk64, 0, stream>>>(
        sampled, nullptr, co_w, co_b, tmp, nullptr, Mq, Cv, Cv, 0);
    ln_residual<<<dim3(Mq), blk256, 0, stream>>>(tgt_a, tmp, ln1_g, ln1_b, tgt_b);

    // 10. FFN + LN3 -> d_out
    gemm_wave<<<dim3(DFFv / 64, Mq / 64), blk64, 0, stream>>>(
        tgt_b, nullptr, f1_w, f1_b, hidden, nullptr, Mq, DFFv, Cv, 1);
    gemm_wave<<<dim3(Cv / 64, Mq / 64), blk64, 0, stream>>>(
        hidden, nullptr, f2_w, f2_b, tmp, nullptr, Mq, Cv, DFFv, 0);
    ln_residual<<<dim3(Mq), blk256, 0, stream>>>(tgt_b, tmp, ln3_g, ln3_b, (float*)d_out);
}